// Round 1
// baseline (1249.458 us; speedup 1.0000x reference)
//
#include <hip/hip_runtime.h>
#include <hip/hip_bf16.h>

#define NN 50000   // nodes
#define NE 100000  // edges
#define NB 512     // graphs
// H = 64, F_NODE = 16, F_EDGE = 8, T = 3

typedef short bf16x8 __attribute__((ext_vector_type(8)));
typedef float f32x4  __attribute__((ext_vector_type(4)));

__device__ __forceinline__ unsigned short f2bs(float f) {
    __hip_bfloat16 h = __float2bfloat16(f);
    union { __hip_bfloat16 b; unsigned short s; } u;
    u.b = h;
    return u.s;
}

__device__ __forceinline__ void cvt2(float f0, float f1, short& o0, short& o1) {
    __hip_bfloat162 bb = __float22bfloat162_rn(make_float2(f0, f1));
    union { __hip_bfloat162 b; short s[2]; } u;
    u.b = bb;
    o0 = u.s[0]; o1 = u.s[1];
}

__device__ __forceinline__ float sigm(float v) { return 1.0f / (1.0f + __expf(-v)); }
__device__ __forceinline__ float tanh_fast(float v) {
    float e = __expf(-2.0f * fabsf(v));
    float t = (1.0f - e) / (1.0f + e);
    return v < 0.f ? -t : t;
}

// x[n][h] = node_features[n] . Win[h] + bin[h]
__global__ __launch_bounds__(256) void node_in_kernel(
    const float* __restrict__ nf, const float* __restrict__ Win,
    const float* __restrict__ bin_, float* __restrict__ x)
{
    int idx = blockIdx.x * 256 + threadIdx.x;
    if (idx >= NN * 64) return;
    int n = idx >> 6, h = idx & 63;
    float acc = bin_[h];
    #pragma unroll
    for (int f = 0; f < 16; f++) acc += nf[n * 16 + f] * Win[h * 16 + f];
    x[idx] = acc;
}

// eh[e][k] = relu(edge_features[e] . We1[k] + be1[k])
__global__ __launch_bounds__(256) void edge_l1_kernel(
    const float* __restrict__ ef, const float* __restrict__ We1,
    const float* __restrict__ be1, float* __restrict__ eh)
{
    int idx = blockIdx.x * 256 + threadIdx.x;
    if (idx >= NE * 64) return;
    int e = idx >> 6, k = idx & 63;
    float acc = be1[k];
    #pragma unroll
    for (int f = 0; f < 8; f++) acc += ef[e * 8 + f] * We1[k * 8 + f];
    eh[idx] = fmaxf(acc, 0.0f);
}

// Repack We2 (+ be2 as K-extension) into bf16 MFMA-B-fragment order:
// Bp[(kt*64 + n)*32 + kk] = B[p = kt*32+kk][n],
// p<4096: B = We2[(n*64 + p>>6)*64 + (p&63)]; p>=4096: B = be2[n*64 + (p-4096)]
__global__ __launch_bounds__(256) void pack_b_kernel(
    const float* __restrict__ We2, const float* __restrict__ be2,
    unsigned short* __restrict__ Bp)
{
    int idx = blockIdx.x * 256 + threadIdx.x;
    if (idx >= 130 * 64 * 32) return;
    int kk = idx & 31;
    int n  = (idx >> 5) & 63;
    int kt = idx >> 11;
    int p  = kt * 32 + kk;
    float v;
    if (p < 4096) {
        int j = p >> 6, k = p & 63;
        v = We2[((size_t)(n * 64 + j)) * 64 + k];
    } else {
        v = be2[n * 64 + (p - 4096)];
    }
    Bp[idx] = f2bs(v);
}

// Fused message GEMM: msg[e][i] = sum_{j,k} We2[i*64+j][k]*xs[e][j]*eh[e][k] (+be2 term),
// scatter-added into agg[Etgt[e]][i]. One wave per 64 edges; A generated in registers.
__global__ __launch_bounds__(64) void msg_kernel(
    const float* __restrict__ x, const float* __restrict__ eh,
    const unsigned short* __restrict__ Bp,
    const int* __restrict__ Esrc, const int* __restrict__ Etgt,
    float* __restrict__ agg)
{
    __shared__ float xs[64 * 68];   // stride 68: 16B-aligned rows, 2-way-max bank alias
    __shared__ int tgt_s[64];
    const int tid = threadIdx.x;
    const int e0 = blockIdx.x * 64;

    {   // stage gathered source-node features, one row per thread
        const int e = e0 + tid;
        const bool ok = (e < NE);
        const int src = ok ? Esrc[e] : 0;
        tgt_s[tid] = ok ? Etgt[e] : -1;
        const float4* xsrc = (const float4*)(x + (size_t)src * 64);
        #pragma unroll
        for (int i = 0; i < 16; i++) {
            float4 v = ok ? xsrc[i] : make_float4(0.f, 0.f, 0.f, 0.f);
            *(float4*)(&xs[tid * 68 + i * 4]) = v;
        }
    }
    __syncthreads();

    const int m = tid & 15;
    const int quad = tid >> 4;

    // per-lane eh cache: k in {quad*8..+8} u {32+quad*8..+8} for 4 m-tiles
    float ehc[4][16];
    #pragma unroll
    for (int mt = 0; mt < 4; mt++) {
        const int e = e0 + mt * 16 + m;
        if (e < NE) {
            const float* b = eh + (size_t)e * 64;
            float4 a0 = *(const float4*)(b + quad * 8);
            float4 a1 = *(const float4*)(b + quad * 8 + 4);
            float4 a2 = *(const float4*)(b + 32 + quad * 8);
            float4 a3 = *(const float4*)(b + 32 + quad * 8 + 4);
            ehc[mt][0]=a0.x; ehc[mt][1]=a0.y; ehc[mt][2]=a0.z; ehc[mt][3]=a0.w;
            ehc[mt][4]=a1.x; ehc[mt][5]=a1.y; ehc[mt][6]=a1.z; ehc[mt][7]=a1.w;
            ehc[mt][8]=a2.x; ehc[mt][9]=a2.y; ehc[mt][10]=a2.z; ehc[mt][11]=a2.w;
            ehc[mt][12]=a3.x; ehc[mt][13]=a3.y; ehc[mt][14]=a3.z; ehc[mt][15]=a3.w;
        } else {
            #pragma unroll
            for (int q = 0; q < 16; q++) ehc[mt][q] = 0.f;
        }
    }

    f32x4 acc[4][4];
    #pragma unroll
    for (int a = 0; a < 4; a++)
        #pragma unroll
        for (int b = 0; b < 4; b++)
            #pragma unroll
            for (int q = 0; q < 4; q++) acc[a][b][q] = 0.f;

    #pragma unroll 1
    for (int j = 0; j < 64; j++) {
        float xsj[4];
        #pragma unroll
        for (int mt = 0; mt < 4; mt++) xsj[mt] = xs[(mt * 16 + m) * 68 + j];
        #pragma unroll
        for (int half = 0; half < 2; half++) {
            const int kt = 2 * j + half;
            bf16x8 bfrag[4];
            #pragma unroll
            for (int nt = 0; nt < 4; nt++)
                bfrag[nt] = *(const bf16x8*)(Bp + (size_t)(kt * 64 + nt * 16 + m) * 32 + quad * 8);
            #pragma unroll
            for (int mt = 0; mt < 4; mt++) {
                bf16x8 af;
                #pragma unroll
                for (int qq = 0; qq < 4; qq++) {
                    short s0, s1;
                    cvt2(xsj[mt] * ehc[mt][half * 8 + 2 * qq],
                         xsj[mt] * ehc[mt][half * 8 + 2 * qq + 1], s0, s1);
                    af[2 * qq] = s0; af[2 * qq + 1] = s1;
                }
                #pragma unroll
                for (int nt = 0; nt < 4; nt++)
                    acc[mt][nt] = __builtin_amdgcn_mfma_f32_16x16x32_bf16(
                        af, bfrag[nt], acc[mt][nt], 0, 0, 0);
            }
        }
    }

    // be2 K-extension (kt = 128,129): A = xs[e][jj], B = be2[i*64+jj]
    #pragma unroll
    for (int half = 0; half < 2; half++) {
        const int kt = 128 + half;
        bf16x8 bfrag[4];
        #pragma unroll
        for (int nt = 0; nt < 4; nt++)
            bfrag[nt] = *(const bf16x8*)(Bp + (size_t)(kt * 64 + nt * 16 + m) * 32 + quad * 8);
        #pragma unroll
        for (int mt = 0; mt < 4; mt++) {
            bf16x8 af;
            #pragma unroll
            for (int qq = 0; qq < 4; qq++) {
                short s0, s1;
                float f0 = xs[(mt * 16 + m) * 68 + half * 32 + quad * 8 + 2 * qq];
                float f1 = xs[(mt * 16 + m) * 68 + half * 32 + quad * 8 + 2 * qq + 1];
                cvt2(f0, f1, s0, s1);
                af[2 * qq] = s0; af[2 * qq + 1] = s1;
            }
            #pragma unroll
            for (int nt = 0; nt < 4; nt++)
                acc[mt][nt] = __builtin_amdgcn_mfma_f32_16x16x32_bf16(
                    af, bfrag[nt], acc[mt][nt], 0, 0, 0);
        }
    }

    // epilogue: C layout col = lane&15 (i), row = quad*4 + reg (edge within tile)
    #pragma unroll
    for (int mt = 0; mt < 4; mt++) {
        #pragma unroll
        for (int r = 0; r < 4; r++) {
            const int row = mt * 16 + quad * 4 + r;
            const int t = tgt_s[row];
            if (t >= 0) {
                #pragma unroll
                for (int nt = 0; nt < 4; nt++)
                    atomicAdd(agg + (size_t)t * 64 + nt * 16 + m, acc[mt][nt][r]);
            }
        }
    }
}

// GRU: x = (1-z)*n + z*x, gates from agg (input) and x (hidden). One lane per node.
__global__ __launch_bounds__(256) void gru_kernel(
    const float* __restrict__ agg, float* __restrict__ x,
    const float* __restrict__ Wih, const float* __restrict__ bih,
    const float* __restrict__ Whh, const float* __restrict__ bhh)
{
    const int node = blockIdx.x * 256 + threadIdx.x;
    if (node >= NN) return;
    float ag[64], xr[64];
    {
        const float4* ap = (const float4*)(agg + (size_t)node * 64);
        const float4* xp = (const float4*)(x + (size_t)node * 64);
        #pragma unroll
        for (int i = 0; i < 16; i++) {
            float4 v = ap[i];
            ag[4*i]=v.x; ag[4*i+1]=v.y; ag[4*i+2]=v.z; ag[4*i+3]=v.w;
            float4 w = xp[i];
            xr[4*i]=w.x; xr[4*i+1]=w.y; xr[4*i+2]=w.z; xr[4*i+3]=w.w;
        }
    }
    #pragma unroll 1
    for (int h = 0; h < 64; h++) {
        float ir = bih[h], iz = bih[64 + h], in_ = bih[128 + h];
        float hr = bhh[h], hz = bhh[64 + h], hn = bhh[128 + h];
        const float4* w0 = (const float4*)(Wih + (size_t)h * 64);
        const float4* w1 = (const float4*)(Wih + (size_t)(64 + h) * 64);
        const float4* w2 = (const float4*)(Wih + (size_t)(128 + h) * 64);
        const float4* v0 = (const float4*)(Whh + (size_t)h * 64);
        const float4* v1 = (const float4*)(Whh + (size_t)(64 + h) * 64);
        const float4* v2 = (const float4*)(Whh + (size_t)(128 + h) * 64);
        #pragma unroll
        for (int kq = 0; kq < 16; kq++) {
            float4 a0 = w0[kq], a1 = w1[kq], a2 = w2[kq];
            float4 b0 = v0[kq], b1 = v1[kq], b2 = v2[kq];
            float g0 = ag[4*kq], g1 = ag[4*kq+1], g2 = ag[4*kq+2], g3 = ag[4*kq+3];
            float h0 = xr[4*kq], h1 = xr[4*kq+1], h2 = xr[4*kq+2], h3 = xr[4*kq+3];
            ir  += a0.x*g0 + a0.y*g1 + a0.z*g2 + a0.w*g3;
            iz  += a1.x*g0 + a1.y*g1 + a1.z*g2 + a1.w*g3;
            in_ += a2.x*g0 + a2.y*g1 + a2.z*g2 + a2.w*g3;
            hr  += b0.x*h0 + b0.y*h1 + b0.z*h2 + b0.w*h3;
            hz  += b1.x*h0 + b1.y*h1 + b1.z*h2 + b1.w*h3;
            hn  += b2.x*h0 + b2.y*h1 + b2.z*h2 + b2.w*h3;
        }
        float r = sigm(ir + hr);
        float z = sigm(iz + hz);
        float n = tanh_fast(in_ + r * hn);
        float xold = x[(size_t)node * 64 + h];     // xr[h] is dynamic-indexed; reload instead
        x[(size_t)node * 64 + h] = (1.0f - z) * n + z * xold;
    }
}

// out[n] = x[n].Wout + bout; pooled[batch[n]] += out[n]
__global__ __launch_bounds__(256) void pool_kernel(
    const float* __restrict__ x, const float* __restrict__ Wout,
    const float* __restrict__ bout, const int* __restrict__ batch,
    float* __restrict__ out)
{
    const int node = blockIdx.x * 256 + threadIdx.x;
    if (node >= NN) return;
    float acc = bout[0];
    const float4* xp = (const float4*)(x + (size_t)node * 64);
    #pragma unroll
    for (int i = 0; i < 16; i++) {
        float4 v = xp[i];
        acc += v.x * Wout[4*i] + v.y * Wout[4*i+1] + v.z * Wout[4*i+2] + v.w * Wout[4*i+3];
    }
    atomicAdd(out + batch[node], acc);
}

extern "C" void kernel_launch(void* const* d_in, const int* in_sizes, int n_in,
                              void* d_out, int out_size, void* d_ws, size_t ws_size,
                              hipStream_t stream)
{
    const float* nf   = (const float*)d_in[0];
    const float* ef   = (const float*)d_in[1];
    const int*   Esrc = (const int*)  d_in[2];
    const int*   Etgt = (const int*)  d_in[3];
    const int*   bat  = (const int*)  d_in[4];
    const float* Win  = (const float*)d_in[5];
    const float* bin_ = (const float*)d_in[6];
    const float* We1  = (const float*)d_in[7];
    const float* be1  = (const float*)d_in[8];
    const float* We2  = (const float*)d_in[9];
    const float* be2  = (const float*)d_in[10];
    const float* Wih  = (const float*)d_in[11];
    const float* bih  = (const float*)d_in[12];
    const float* Whh  = (const float*)d_in[13];
    const float* bhh  = (const float*)d_in[14];
    const float* Wout = (const float*)d_in[15];
    const float* bout = (const float*)d_in[16];

    char* ws = (char*)d_ws;
    float* x            = (float*)(ws);               // 12.8 MB
    float* agg          = (float*)(ws + 12800000);    // 12.8 MB
    float* eh           = (float*)(ws + 25600000);    // 25.6 MB
    unsigned short* Bp  = (unsigned short*)(ws + 51200000); // 520.0 KB -> total ~51.7 MB

    hipMemsetAsync(d_out, 0, NB * sizeof(float), stream);

    node_in_kernel<<<(NN * 64 + 255) / 256, 256, 0, stream>>>(nf, Win, bin_, x);
    edge_l1_kernel<<<(NE * 64 + 255) / 256, 256, 0, stream>>>(ef, We1, be1, eh);
    pack_b_kernel<<<(130 * 64 * 32 + 255) / 256, 256, 0, stream>>>(We2, be2, Bp);

    for (int t = 0; t < 3; t++) {
        hipMemsetAsync(agg, 0, (size_t)NN * 64 * sizeof(float), stream);
        msg_kernel<<<(NE + 63) / 64, 64, 0, stream>>>(x, eh, Bp, Esrc, Etgt, agg);
        gru_kernel<<<(NN + 255) / 256, 256, 0, stream>>>(agg, x, Wih, bih, Whh, bhh);
    }

    pool_kernel<<<(NN + 255) / 256, 256, 0, stream>>>(x, Wout, bout, bat, (float*)d_out);
}

// Round 2
// 641.457 us; speedup vs baseline: 1.9478x; 1.9478x over previous
//
#include <hip/hip_runtime.h>
#include <hip/hip_bf16.h>

#define NN 50000   // nodes
#define NE 100000  // edges
#define NB 512     // graphs
// H = 64, F_NODE = 16, F_EDGE = 8, T = 3

typedef short bf16x8 __attribute__((ext_vector_type(8)));
typedef float f32x4  __attribute__((ext_vector_type(4)));

__device__ __forceinline__ unsigned short f2bs(float f) {
    __hip_bfloat16 h = __float2bfloat16(f);
    union { __hip_bfloat16 b; unsigned short s; } u;
    u.b = h;
    return u.s;
}

__device__ __forceinline__ void cvt2(float f0, float f1, short& o0, short& o1) {
    __hip_bfloat162 bb = __float22bfloat162_rn(make_float2(f0, f1));
    union { __hip_bfloat162 b; short s[2]; } u;
    u.b = bb;
    o0 = u.s[0]; o1 = u.s[1];
}

__device__ __forceinline__ float sigm(float v) { return 1.0f / (1.0f + __expf(-v)); }
__device__ __forceinline__ float tanh_fast(float v) {
    float e = __expf(-2.0f * fabsf(v));
    float t = (1.0f - e) / (1.0f + e);
    return v < 0.f ? -t : t;
}

// x[n][h] = node_features[n] . Win[h] + bin[h]
__global__ __launch_bounds__(256) void node_in_kernel(
    const float* __restrict__ nf, const float* __restrict__ Win,
    const float* __restrict__ bin_, float* __restrict__ x)
{
    int idx = blockIdx.x * 256 + threadIdx.x;
    if (idx >= NN * 64) return;
    int n = idx >> 6, h = idx & 63;
    float acc = bin_[h];
    #pragma unroll
    for (int f = 0; f < 16; f++) acc += nf[n * 16 + f] * Win[h * 16 + f];
    x[idx] = acc;
}

// eh[e][k] = relu(edge_features[e] . We1[k] + be1[k])
__global__ __launch_bounds__(256) void edge_l1_kernel(
    const float* __restrict__ ef, const float* __restrict__ We1,
    const float* __restrict__ be1, float* __restrict__ eh)
{
    int idx = blockIdx.x * 256 + threadIdx.x;
    if (idx >= NE * 64) return;
    int e = idx >> 6, k = idx & 63;
    float acc = be1[k];
    #pragma unroll
    for (int f = 0; f < 8; f++) acc += ef[e * 8 + f] * We1[k * 8 + f];
    eh[idx] = fmaxf(acc, 0.0f);
}

// Repack We2 (+ be2 as K-extension) into bf16 MFMA-B-fragment order:
// Bp[(kt*64 + n)*32 + kk] = B[p = kt*32+kk][n]
__global__ __launch_bounds__(256) void pack_b_kernel(
    const float* __restrict__ We2, const float* __restrict__ be2,
    unsigned short* __restrict__ Bp)
{
    int idx = blockIdx.x * 256 + threadIdx.x;
    if (idx >= 130 * 64 * 32) return;
    int kk = idx & 31;
    int n  = (idx >> 5) & 63;
    int kt = idx >> 11;
    int p  = kt * 32 + kk;
    float v;
    if (p < 4096) {
        int j = p >> 6, k = p & 63;
        v = We2[((size_t)(n * 64 + j)) * 64 + k];
    } else {
        v = be2[n * 64 + (p - 4096)];
    }
    Bp[idx] = f2bs(v);
}

// Repack GRU weights: WT[(k*64+h)*8 + g], g = {Wih[h][k], Wih[64+h][k], Wih[128+h][k],
//                                              Whh[h][k], Whh[64+h][k], Whh[128+h][k], 0, 0}
__global__ __launch_bounds__(256) void pack_gru_kernel(
    const float* __restrict__ Wih, const float* __restrict__ Whh,
    float* __restrict__ WT)
{
    int idx = blockIdx.x * 256 + threadIdx.x;  // over 64*64 (k,h)
    if (idx >= 64 * 64) return;
    int h = idx & 63, k = idx >> 6;
    float* o = WT + (size_t)idx * 8;
    o[0] = Wih[(size_t)h * 64 + k];
    o[1] = Wih[(size_t)(64 + h) * 64 + k];
    o[2] = Wih[(size_t)(128 + h) * 64 + k];
    o[3] = Whh[(size_t)h * 64 + k];
    o[4] = Whh[(size_t)(64 + h) * 64 + k];
    o[5] = Whh[(size_t)(128 + h) * 64 + k];
    o[6] = 0.f; o[7] = 0.f;
}

// Fused message GEMM: msg[e][i] = sum_{j,k} We2[i*64+j][k]*xs[e][j]*eh[e][k] (+be2 term),
// scatter-added into agg[Etgt[e]][i]. One wave per 64 edges; A generated in registers.
__global__ __launch_bounds__(64) void msg_kernel(
    const float* __restrict__ x, const float* __restrict__ eh,
    const unsigned short* __restrict__ Bp,
    const int* __restrict__ Esrc, const int* __restrict__ Etgt,
    float* __restrict__ agg)
{
    __shared__ float xs[64 * 68];
    __shared__ int tgt_s[64];
    const int tid = threadIdx.x;
    const int e0 = blockIdx.x * 64;

    {
        const int e = e0 + tid;
        const bool ok = (e < NE);
        const int src = ok ? Esrc[e] : 0;
        tgt_s[tid] = ok ? Etgt[e] : -1;
        const float4* xsrc = (const float4*)(x + (size_t)src * 64);
        #pragma unroll
        for (int i = 0; i < 16; i++) {
            float4 v = ok ? xsrc[i] : make_float4(0.f, 0.f, 0.f, 0.f);
            *(float4*)(&xs[tid * 68 + i * 4]) = v;
        }
    }
    __syncthreads();

    const int m = tid & 15;
    const int quad = tid >> 4;

    float ehc[4][16];
    #pragma unroll
    for (int mt = 0; mt < 4; mt++) {
        const int e = e0 + mt * 16 + m;
        if (e < NE) {
            const float* b = eh + (size_t)e * 64;
            float4 a0 = *(const float4*)(b + quad * 8);
            float4 a1 = *(const float4*)(b + quad * 8 + 4);
            float4 a2 = *(const float4*)(b + 32 + quad * 8);
            float4 a3 = *(const float4*)(b + 32 + quad * 8 + 4);
            ehc[mt][0]=a0.x; ehc[mt][1]=a0.y; ehc[mt][2]=a0.z; ehc[mt][3]=a0.w;
            ehc[mt][4]=a1.x; ehc[mt][5]=a1.y; ehc[mt][6]=a1.z; ehc[mt][7]=a1.w;
            ehc[mt][8]=a2.x; ehc[mt][9]=a2.y; ehc[mt][10]=a2.z; ehc[mt][11]=a2.w;
            ehc[mt][12]=a3.x; ehc[mt][13]=a3.y; ehc[mt][14]=a3.z; ehc[mt][15]=a3.w;
        } else {
            #pragma unroll
            for (int q = 0; q < 16; q++) ehc[mt][q] = 0.f;
        }
    }

    f32x4 acc[4][4];
    #pragma unroll
    for (int a = 0; a < 4; a++)
        #pragma unroll
        for (int b = 0; b < 4; b++)
            #pragma unroll
            for (int q = 0; q < 4; q++) acc[a][b][q] = 0.f;

    #pragma unroll 1
    for (int j = 0; j < 64; j++) {
        float xsj[4];
        #pragma unroll
        for (int mt = 0; mt < 4; mt++) xsj[mt] = xs[(mt * 16 + m) * 68 + j];
        #pragma unroll
        for (int half = 0; half < 2; half++) {
            const int kt = 2 * j + half;
            bf16x8 bfrag[4];
            #pragma unroll
            for (int nt = 0; nt < 4; nt++)
                bfrag[nt] = *(const bf16x8*)(Bp + (size_t)(kt * 64 + nt * 16 + m) * 32 + quad * 8);
            #pragma unroll
            for (int mt = 0; mt < 4; mt++) {
                bf16x8 af;
                #pragma unroll
                for (int qq = 0; qq < 4; qq++) {
                    short s0, s1;
                    cvt2(xsj[mt] * ehc[mt][half * 8 + 2 * qq],
                         xsj[mt] * ehc[mt][half * 8 + 2 * qq + 1], s0, s1);
                    af[2 * qq] = s0; af[2 * qq + 1] = s1;
                }
                #pragma unroll
                for (int nt = 0; nt < 4; nt++)
                    acc[mt][nt] = __builtin_amdgcn_mfma_f32_16x16x32_bf16(
                        af, bfrag[nt], acc[mt][nt], 0, 0, 0);
            }
        }
    }

    // be2 K-extension (kt = 128,129)
    #pragma unroll
    for (int half = 0; half < 2; half++) {
        const int kt = 128 + half;
        bf16x8 bfrag[4];
        #pragma unroll
        for (int nt = 0; nt < 4; nt++)
            bfrag[nt] = *(const bf16x8*)(Bp + (size_t)(kt * 64 + nt * 16 + m) * 32 + quad * 8);
        #pragma unroll
        for (int mt = 0; mt < 4; mt++) {
            bf16x8 af;
            #pragma unroll
            for (int qq = 0; qq < 4; qq++) {
                short s0, s1;
                float f0 = xs[(mt * 16 + m) * 68 + half * 32 + quad * 8 + 2 * qq];
                float f1 = xs[(mt * 16 + m) * 68 + half * 32 + quad * 8 + 2 * qq + 1];
                cvt2(f0, f1, s0, s1);
                af[2 * qq] = s0; af[2 * qq + 1] = s1;
            }
            #pragma unroll
            for (int nt = 0; nt < 4; nt++)
                acc[mt][nt] = __builtin_amdgcn_mfma_f32_16x16x32_bf16(
                    af, bfrag[nt], acc[mt][nt], 0, 0, 0);
        }
    }

    #pragma unroll
    for (int mt = 0; mt < 4; mt++) {
        #pragma unroll
        for (int r = 0; r < 4; r++) {
            const int row = mt * 16 + quad * 4 + r;
            const int t = tgt_s[row];
            if (t >= 0) {
                #pragma unroll
                for (int nt = 0; nt < 4; nt++)
                    atomicAdd(agg + (size_t)t * 64 + nt * 16 + m, acc[mt][nt][r]);
            }
        }
    }
}

// GRU v2: thread = (node, h); 4 waves/block, each wave handles 4 nodes (16/block).
// agg & x rows interleaved in LDS; transposed gate-packed weights WT streamed (L1/L2-hit).
__global__ __launch_bounds__(256) void gru_kernel(
    const float* __restrict__ agg, float* __restrict__ x,
    const float* __restrict__ WT, const float* __restrict__ bih,
    const float* __restrict__ bhh)
{
    __shared__ float axs[16][128];   // [node_local][k*2 + {0:agg, 1:x}]
    const int tid = threadIdx.x;
    const int wave = tid >> 6, lane = tid & 63;
    const int node0 = blockIdx.x * 16;

    // stage: 16 nodes x (64 agg + 64 x) = 2048 floats, 8 per thread, coalesced
    #pragma unroll
    for (int i = 0; i < 8; i++) {
        int idx = i * 256 + tid;
        int nn = idx >> 7, kk = idx & 127;
        int node = node0 + nn;
        float v = 0.f;
        if (node < NN) v = (kk < 64) ? agg[(size_t)node * 64 + kk]
                                     : x[(size_t)node * 64 + (kk - 64)];
        axs[nn][(kk & 63) * 2 + (kk >> 6)] = v;
    }
    __syncthreads();

    const float b_ir = bih[lane], b_iz = bih[64 + lane], b_in = bih[128 + lane];
    const float b_hr = bhh[lane], b_hz = bhh[64 + lane], b_hn = bhh[128 + lane];

    float ir[4], iz[4], in_[4], hr[4], hz[4], hn[4];
    #pragma unroll
    for (int nn = 0; nn < 4; nn++) {
        ir[nn] = b_ir; iz[nn] = b_iz; in_[nn] = b_in;
        hr[nn] = b_hr; hz[nn] = b_hz; hn[nn] = b_hn;
    }

    #pragma unroll 4
    for (int k = 0; k < 64; k++) {
        const float4 wA = *(const float4*)(WT + ((size_t)(k * 64 + lane)) * 8);
        const float4 wB = *(const float4*)(WT + ((size_t)(k * 64 + lane)) * 8 + 4);
        #pragma unroll
        for (int nn = 0; nn < 4; nn++) {
            float2 ax = *(const float2*)(&axs[wave * 4 + nn][k * 2]);
            ir[nn]  += wA.x * ax.x;
            iz[nn]  += wA.y * ax.x;
            in_[nn] += wA.z * ax.x;
            hr[nn]  += wA.w * ax.y;
            hz[nn]  += wB.x * ax.y;
            hn[nn]  += wB.y * ax.y;
        }
    }

    #pragma unroll
    for (int nn = 0; nn < 4; nn++) {
        const int node = node0 + wave * 4 + nn;
        if (node >= NN) continue;
        float r = sigm(ir[nn] + hr[nn]);
        float z = sigm(iz[nn] + hz[nn]);
        float n = tanh_fast(in_[nn] + r * hn[nn]);
        float xold = axs[wave * 4 + nn][lane * 2 + 1];
        x[(size_t)node * 64 + lane] = (1.0f - z) * n + z * xold;
    }
}

// out[n] = x[n].Wout + bout; pooled[batch[n]] += out[n]
__global__ __launch_bounds__(256) void pool_kernel(
    const float* __restrict__ x, const float* __restrict__ Wout,
    const float* __restrict__ bout, const int* __restrict__ batch,
    float* __restrict__ out)
{
    const int node = blockIdx.x * 256 + threadIdx.x;
    if (node >= NN) return;
    float acc = bout[0];
    const float4* xp = (const float4*)(x + (size_t)node * 64);
    #pragma unroll
    for (int i = 0; i < 16; i++) {
        float4 v = xp[i];
        acc += v.x * Wout[4*i] + v.y * Wout[4*i+1] + v.z * Wout[4*i+2] + v.w * Wout[4*i+3];
    }
    atomicAdd(out + batch[node], acc);
}

extern "C" void kernel_launch(void* const* d_in, const int* in_sizes, int n_in,
                              void* d_out, int out_size, void* d_ws, size_t ws_size,
                              hipStream_t stream)
{
    const float* nf   = (const float*)d_in[0];
    const float* ef   = (const float*)d_in[1];
    const int*   Esrc = (const int*)  d_in[2];
    const int*   Etgt = (const int*)  d_in[3];
    const int*   bat  = (const int*)  d_in[4];
    const float* Win  = (const float*)d_in[5];
    const float* bin_ = (const float*)d_in[6];
    const float* We1  = (const float*)d_in[7];
    const float* be1  = (const float*)d_in[8];
    const float* We2  = (const float*)d_in[9];
    const float* be2  = (const float*)d_in[10];
    const float* Wih  = (const float*)d_in[11];
    const float* bih  = (const float*)d_in[12];
    const float* Whh  = (const float*)d_in[13];
    const float* bhh  = (const float*)d_in[14];
    const float* Wout = (const float*)d_in[15];
    const float* bout = (const float*)d_in[16];

    char* ws = (char*)d_ws;
    float* x            = (float*)(ws);               // 12.8 MB
    float* agg          = (float*)(ws + 12800000);    // 12.8 MB
    float* eh           = (float*)(ws + 25600000);    // 25.6 MB
    unsigned short* Bp  = (unsigned short*)(ws + 51200000); // 532 KB
    float* WT           = (float*)(ws + 51800000);    // 128 KB -> total ~52 MB

    hipMemsetAsync(d_out, 0, NB * sizeof(float), stream);

    node_in_kernel<<<(NN * 64 + 255) / 256, 256, 0, stream>>>(nf, Win, bin_, x);
    edge_l1_kernel<<<(NE * 64 + 255) / 256, 256, 0, stream>>>(ef, We1, be1, eh);
    pack_b_kernel<<<(130 * 64 * 32 + 255) / 256, 256, 0, stream>>>(We2, be2, Bp);
    pack_gru_kernel<<<(64 * 64 + 255) / 256, 256, 0, stream>>>(Wih, Whh, WT);

    for (int t = 0; t < 3; t++) {
        hipMemsetAsync(agg, 0, (size_t)NN * 64 * sizeof(float), stream);
        msg_kernel<<<(NE + 63) / 64, 64, 0, stream>>>(x, eh, Bp, Esrc, Etgt, agg);
        gru_kernel<<<(NN + 15) / 16, 256, 0, stream>>>(agg, x, WT, bih, bhh);
    }

    pool_kernel<<<(NN + 255) / 256, 256, 0, stream>>>(x, Wout, bout, bat, (float*)d_out);
}

// Round 3
// 476.753 us; speedup vs baseline: 2.6208x; 1.3455x over previous
//
#include <hip/hip_runtime.h>
#include <hip/hip_fp16.h>

#define NN 50000   // nodes
#define NE 100000  // edges
#define NB 512     // graphs
// H = 64, F_NODE = 16, F_EDGE = 8, T = 3

typedef _Float16 f16x8 __attribute__((ext_vector_type(8)));
typedef float f32x4  __attribute__((ext_vector_type(4)));

__device__ __forceinline__ float sigm(float v) { return 1.0f / (1.0f + __expf(-v)); }
__device__ __forceinline__ float tanh_fast(float v) {
    float e = __expf(-2.0f * fabsf(v));
    float t = (1.0f - e) / (1.0f + e);
    return v < 0.f ? -t : t;
}

// x[n][h] = node_features[n] . Win[h] + bin[h]; also write f16 copy xh
__global__ __launch_bounds__(256) void node_in_kernel(
    const float* __restrict__ nf, const float* __restrict__ Win,
    const float* __restrict__ bin_, float* __restrict__ x, __half* __restrict__ xh)
{
    int idx = blockIdx.x * 256 + threadIdx.x;
    if (idx >= NN * 64) return;
    int n = idx >> 6, h = idx & 63;
    float acc = bin_[h];
    #pragma unroll
    for (int f = 0; f < 16; f++) acc += nf[n * 16 + f] * Win[h * 16 + f];
    x[idx] = acc;
    xh[idx] = __float2half(acc);
}

// ehh[e][k] = f16(relu(edge_features[e] . We1[k] + be1[k]))
__global__ __launch_bounds__(256) void edge_l1_kernel(
    const float* __restrict__ ef, const float* __restrict__ We1,
    const float* __restrict__ be1, __half* __restrict__ ehh)
{
    int idx = blockIdx.x * 256 + threadIdx.x;
    if (idx >= NE * 64) return;
    int e = idx >> 6, k = idx & 63;
    float acc = be1[k];
    #pragma unroll
    for (int f = 0; f < 8; f++) acc += ef[e * 8 + f] * We1[k * 8 + f];
    ehh[idx] = __float2half(fmaxf(acc, 0.0f));
}

// Pack We2 (+ be2 K-extension) into f16 MFMA-B-fragment order:
// Bp[(kt*64 + n)*32 + kk], p = kt*32+kk; p<4096: We2[(n*64 + (p>>6))*64 + (p&63)]
__global__ __launch_bounds__(256) void pack_b_kernel(
    const float* __restrict__ We2, const float* __restrict__ be2,
    __half* __restrict__ Bp)
{
    int idx = blockIdx.x * 256 + threadIdx.x;
    if (idx >= 130 * 64 * 32) return;
    int kk = idx & 31;
    int n  = (idx >> 5) & 63;
    int kt = idx >> 11;
    int p  = kt * 32 + kk;
    float v;
    if (p < 4096) {
        int j = p >> 6, k = p & 63;
        v = We2[((size_t)(n * 64 + j)) * 64 + k];
    } else {
        v = be2[n * 64 + (p - 4096)];
    }
    Bp[idx] = __float2half(v);
}

// Pack GRU weights into f16 B-frag layout WG[kt][nt][n][kk]:
// cols 0..383 = [i_r,i_z,i_n](Wih) ++ [h_r,h_z,h_n](Whh); nt tile = 16 cols; kt: K=64 in 2x32
__global__ __launch_bounds__(256) void pack_gru_kernel(
    const float* __restrict__ Wih, const float* __restrict__ Whh,
    __half* __restrict__ WG)
{
    int idx = blockIdx.x * 256 + threadIdx.x;   // 2*24*16*32 = 24576
    if (idx >= 24576) return;
    int kk = idx & 31;
    int n  = (idx >> 5) & 15;
    int nt = (idx >> 9) % 24;
    int kt = (idx >> 9) / 24;
    int k = kt * 32 + kk;
    int col192 = (nt % 12) * 16 + n;
    int gate = col192 >> 6, h = col192 & 63;
    const float* src = (nt < 12) ? Wih : Whh;
    WG[idx] = __float2half(src[((size_t)(gate * 64 + h)) * 64 + k]);
}

// Fused message GEMM, f16: msg[e][i] = sum_{j,k} We2[i*64+j][k]*x[src][j]*eh[e][k] (+be2.x)
// Block = 4 waves x 64 edges. A generated via v_pk_mul_f16; scatter-add into agg.
__global__ __launch_bounds__(256, 3) void msg_kernel(
    const __half* __restrict__ xh, const __half* __restrict__ ehh,
    const __half* __restrict__ Bp,
    const int* __restrict__ Esrc, const int* __restrict__ Etgt,
    float* __restrict__ agg)
{
    __shared__ __half xs[4][64][72];   // 72: rows 144B (16B-aligned), 2-way bank alias only
    __shared__ int tgt_s[256];
    const int tid = threadIdx.x;
    const int e0 = blockIdx.x * 256;
    const int w = tid >> 6, lane = tid & 63;

    {   // stage one gathered f16 source row per thread
        const int e = e0 + tid;
        const bool ok = (e < NE);
        const int src = ok ? Esrc[e] : 0;
        tgt_s[tid] = ok ? Etgt[e] : -1;
        const uint4* xsrc = (const uint4*)(xh + (size_t)src * 64);
        #pragma unroll
        for (int i = 0; i < 8; i++) {
            uint4 v = ok ? xsrc[i] : make_uint4(0, 0, 0, 0);
            *(uint4*)(&xs[w][lane][i * 8]) = v;
        }
    }
    __syncthreads();

    const int m = lane & 15;
    const int quad = lane >> 4;

    // per-lane eh f16 cache: pairs for k in {quad*8..+8} u {32+quad*8..+8}, 4 m-tiles
    __half2 ehc2[4][2][4];
    #pragma unroll
    for (int mt = 0; mt < 4; mt++) {
        const int e = e0 + w * 64 + mt * 16 + m;
        if (e < NE) {
            union { uint4 u; __half2 h[4]; } u0, u1;
            u0.u = *(const uint4*)(ehh + (size_t)e * 64 + quad * 8);
            u1.u = *(const uint4*)(ehh + (size_t)e * 64 + 32 + quad * 8);
            #pragma unroll
            for (int q = 0; q < 4; q++) { ehc2[mt][0][q] = u0.h[q]; ehc2[mt][1][q] = u1.h[q]; }
        } else {
            __half2 z = __halves2half2(__float2half(0.f), __float2half(0.f));
            #pragma unroll
            for (int q = 0; q < 4; q++) { ehc2[mt][0][q] = z; ehc2[mt][1][q] = z; }
        }
    }

    f32x4 acc[4][4];
    #pragma unroll
    for (int a = 0; a < 4; a++)
        #pragma unroll
        for (int b = 0; b < 4; b++)
            #pragma unroll
            for (int q = 0; q < 4; q++) acc[a][b][q] = 0.f;

    const __half* blane = Bp + m * 32 + quad * 8;

    #pragma unroll 1
    for (int j = 0; j < 64; j++) {
        __half2 xsj2[4];
        #pragma unroll
        for (int mt = 0; mt < 4; mt++) {
            __half v = xs[w][mt * 16 + m][j];
            xsj2[mt] = __halves2half2(v, v);
        }
        #pragma unroll
        for (int half = 0; half < 2; half++) {
            const int kt = 2 * j + half;
            f16x8 bfrag[4];
            #pragma unroll
            for (int nt = 0; nt < 4; nt++)
                bfrag[nt] = *(const f16x8*)(blane + (size_t)kt * 2048 + nt * 512);
            #pragma unroll
            for (int mt = 0; mt < 4; mt++) {
                union { __half2 h[4]; f16x8 v; } u;
                #pragma unroll
                for (int q = 0; q < 4; q++)
                    u.h[q] = __hmul2(xsj2[mt], ehc2[mt][half][q]);
                #pragma unroll
                for (int nt = 0; nt < 4; nt++)
                    acc[mt][nt] = __builtin_amdgcn_mfma_f32_16x16x32_f16(
                        u.v, bfrag[nt], acc[mt][nt], 0, 0, 0);
            }
        }
    }

    // be2 K-extension (kt = 128,129): A = xs row chunk (direct b128 read)
    #pragma unroll
    for (int half = 0; half < 2; half++) {
        const int kt = 128 + half;
        f16x8 bfrag[4];
        #pragma unroll
        for (int nt = 0; nt < 4; nt++)
            bfrag[nt] = *(const f16x8*)(blane + (size_t)kt * 2048 + nt * 512);
        #pragma unroll
        for (int mt = 0; mt < 4; mt++) {
            f16x8 af = *(const f16x8*)(&xs[w][mt * 16 + m][half * 32 + quad * 8]);
            #pragma unroll
            for (int nt = 0; nt < 4; nt++)
                acc[mt][nt] = __builtin_amdgcn_mfma_f32_16x16x32_f16(
                    af, bfrag[nt], acc[mt][nt], 0, 0, 0);
        }
    }

    // C layout: col = lane&15 (i), row = quad*4 + reg (edge in tile)
    #pragma unroll
    for (int mt = 0; mt < 4; mt++) {
        #pragma unroll
        for (int r = 0; r < 4; r++) {
            const int row = w * 64 + mt * 16 + quad * 4 + r;
            const int t = tgt_s[row];
            if (t >= 0) {
                #pragma unroll
                for (int nt = 0; nt < 4; nt++)
                    atomicAdd(agg + (size_t)t * 64 + nt * 16 + m, acc[mt][nt][r]);
            }
        }
    }
}

// GRU via MFMA: wave = 16 nodes x 384 gate-cols (K=64). Weights LDS-staged once/block.
__global__ __launch_bounds__(256, 3) void gru_kernel(
    const float* __restrict__ agg, float* __restrict__ x, __half* __restrict__ xh,
    const __half* __restrict__ WG,
    const float* __restrict__ bih, const float* __restrict__ bhh)
{
    __shared__ __half wlds[24576];   // 48 KB
    const int tid = threadIdx.x;
    {
        const uint4* src = (const uint4*)WG;
        uint4* dst = (uint4*)wlds;
        #pragma unroll
        for (int i = 0; i < 12; i++) dst[i * 256 + tid] = src[i * 256 + tid];
    }
    __syncthreads();

    const int w = tid >> 6, lane = tid & 63, m = lane & 15, quad = lane >> 4;
    const int nbase = blockIdx.x * 64 + w * 16;
    const int anode = nbase + m;           // A-operand row
    const bool aok = (anode < NN);

    f16x8 a_agg[2], a_x[2];
    #pragma unroll
    for (int kt = 0; kt < 2; kt++) {
        const int koff = kt * 32 + quad * 8;
        if (aok) {
            const float* ap = agg + (size_t)anode * 64 + koff;
            float4 f0 = *(const float4*)ap;
            float4 f1 = *(const float4*)(ap + 4);
            union { __half2 h[4]; f16x8 v; } u;
            u.h[0] = __floats2half2_rn(f0.x, f0.y);
            u.h[1] = __floats2half2_rn(f0.z, f0.w);
            u.h[2] = __floats2half2_rn(f1.x, f1.y);
            u.h[3] = __floats2half2_rn(f1.z, f1.w);
            a_agg[kt] = u.v;
            a_x[kt] = *(const f16x8*)(xh + (size_t)anode * 64 + koff);
        } else {
            f16x8 z;
            #pragma unroll
            for (int i = 0; i < 8; i++) z[i] = (_Float16)0;
            a_agg[kt] = z; a_x[kt] = z;
        }
    }

    f32x4 acc[24];
    #pragma unroll
    for (int nt = 0; nt < 24; nt++)
        #pragma unroll
        for (int q = 0; q < 4; q++) acc[nt][q] = 0.f;

    #pragma unroll
    for (int kt = 0; kt < 2; kt++) {
        #pragma unroll
        for (int nt = 0; nt < 24; nt++) {
            f16x8 b = *(const f16x8*)(wlds + (kt * 24 + nt) * 512 + m * 32 + quad * 8);
            acc[nt] = __builtin_amdgcn_mfma_f32_16x16x32_f16(
                (nt < 12) ? a_agg[kt] : a_x[kt], b, acc[nt], 0, 0, 0);
        }
    }

    // epilogue: node = quad*4 + r (C row), h = t*16 + m (C col)
    #pragma unroll
    for (int t = 0; t < 4; t++) {
        const int h = t * 16 + m;
        const float bir = bih[h], biz = bih[64 + h], bin = bih[128 + h];
        const float bhr = bhh[h], bhz = bhh[64 + h], bhn = bhh[128 + h];
        #pragma unroll
        for (int r = 0; r < 4; r++) {
            const int nd = nbase + quad * 4 + r;
            if (nd >= NN) continue;
            float ir  = acc[t][r]      + bir;
            float iz  = acc[4 + t][r]  + biz;
            float in_ = acc[8 + t][r]  + bin;
            float hr  = acc[12 + t][r] + bhr;
            float hz  = acc[16 + t][r] + bhz;
            float hn  = acc[20 + t][r] + bhn;
            float rg = sigm(ir + hr);
            float z  = sigm(iz + hz);
            float n  = tanh_fast(in_ + rg * hn);
            float xold = x[(size_t)nd * 64 + h];
            float xn = (1.0f - z) * n + z * xold;
            x[(size_t)nd * 64 + h] = xn;
            xh[(size_t)nd * 64 + h] = __float2half(xn);
        }
    }
}

// out[n] = x[n].Wout + bout; pooled[batch[n]] += out[n]
__global__ __launch_bounds__(256) void pool_kernel(
    const float* __restrict__ x, const float* __restrict__ Wout,
    const float* __restrict__ bout, const int* __restrict__ batch,
    float* __restrict__ out)
{
    const int node = blockIdx.x * 256 + threadIdx.x;
    if (node >= NN) return;
    float acc = bout[0];
    const float4* xp = (const float4*)(x + (size_t)node * 64);
    #pragma unroll
    for (int i = 0; i < 16; i++) {
        float4 v = xp[i];
        acc += v.x * Wout[4*i] + v.y * Wout[4*i+1] + v.z * Wout[4*i+2] + v.w * Wout[4*i+3];
    }
    atomicAdd(out + batch[node], acc);
}

extern "C" void kernel_launch(void* const* d_in, const int* in_sizes, int n_in,
                              void* d_out, int out_size, void* d_ws, size_t ws_size,
                              hipStream_t stream)
{
    const float* nf   = (const float*)d_in[0];
    const float* ef   = (const float*)d_in[1];
    const int*   Esrc = (const int*)  d_in[2];
    const int*   Etgt = (const int*)  d_in[3];
    const int*   bat  = (const int*)  d_in[4];
    const float* Win  = (const float*)d_in[5];
    const float* bin_ = (const float*)d_in[6];
    const float* We1  = (const float*)d_in[7];
    const float* be1  = (const float*)d_in[8];
    const float* We2  = (const float*)d_in[9];
    const float* be2  = (const float*)d_in[10];
    const float* Wih  = (const float*)d_in[11];
    const float* bih  = (const float*)d_in[12];
    const float* Whh  = (const float*)d_in[13];
    const float* bhh  = (const float*)d_in[14];
    const float* Wout = (const float*)d_in[15];
    const float* bout = (const float*)d_in[16];

    char* ws = (char*)d_ws;
    float*  x   = (float*)(ws);                       // 12.8 MB
    float*  agg = (float*)(ws + 12800000);            // 12.8 MB
    __half* xh  = (__half*)(ws + 25600000);           // 6.4 MB
    __half* ehh = (__half*)(ws + 32000000);           // 12.8 MB
    __half* Bp  = (__half*)(ws + 44800000);           // 532,480 B
    __half* WG  = (__half*)(ws + 45400064);           // 49,152 B

    hipMemsetAsync(d_out, 0, NB * sizeof(float), stream);

    node_in_kernel<<<(NN * 64 + 255) / 256, 256, 0, stream>>>(nf, Win, bin_, x, xh);
    edge_l1_kernel<<<(NE * 64 + 255) / 256, 256, 0, stream>>>(ef, We1, be1, ehh);
    pack_b_kernel<<<(130 * 64 * 32 + 255) / 256, 256, 0, stream>>>(We2, be2, Bp);
    pack_gru_kernel<<<(24576 + 255) / 256, 256, 0, stream>>>(Wih, Whh, WG);

    for (int t = 0; t < 3; t++) {
        hipMemsetAsync(agg, 0, (size_t)NN * 64 * sizeof(float), stream);
        msg_kernel<<<(NE + 255) / 256, 256, 0, stream>>>(xh, ehh, Bp, Esrc, Etgt, agg);
        gru_kernel<<<(NN + 63) / 64, 256, 0, stream>>>(agg, x, xh, WG, bih, bhh);
    }

    pool_kernel<<<(NN + 255) / 256, 256, 0, stream>>>(x, Wout, bout, bat, (float*)d_out);
}